// Round 12
// baseline (372.896 us; speedup 1.0000x reference)
//
#include <hip/hip_runtime.h>
#include <hip/hip_bf16.h>
#include <hip/hip_fp16.h>

typedef _Float16 f16;
typedef _Float16 f16x8 __attribute__((ext_vector_type(8)));
typedef float f32x4 __attribute__((ext_vector_type(4)));

#define SP 16384             // 128*128 spatial per batch
#define NTILES 4096
#define XF_BYTES ((size_t)NTILES * 40960)

// xf tile layout (40 KB per 16-spatial tile, fragment-ready, LANE-LINEAR):
//   byte = t*8192 + k0*1024 + g4*256 + c*16 + e*2
//   holds x[t, d=k0*32+g4*8+e, s=tile*16+c]
// as_ layout (8 KB, proj-A-fragment-ready): feat,s ->
//   byte = (feat>>5)*1024 + ((feat>>3)&3)*256 + s*16 + (feat&7)*2

__global__ void prep_weights(const float* __restrict__ Wq,
                             const float* __restrict__ Wkv,
                             const float* __restrict__ Wp,
                             f16* __restrict__ wqT,
                             f16* __restrict__ wkvT,
                             f16* __restrict__ wpT) {
  const int f = threadIdx.x;
  const int k = blockIdx.x;
  wkvT[f * 256 + k] = (f16)Wkv[k * 512 + f];
  if (f < 256) {
    wqT[f * 256 + k] = (f16)Wq[k * 256 + f];
    wpT[f * 256 + k] = (f16)Wp[k * 256 + f];
  }
}

// Mega kernel: 256 blocks x 1024 threads, 1 block/CU (LDS 88 KB).
// Block owns 16 consecutive tiles (one 256-s chunk of one batch).
// Phase 1: transpose own x slice -> own xf slice (block-local, L2/L3-hot).
// Phase 2: per tile, double-buffered: stage(i+1) || {qkv k-loop, attention,
// proj (all 16 heads in-block)}. Wave = 1 head. acc 44 regs; (1024,4) cap 128.
__global__ __launch_bounds__(1024, 4) void mega(
    const float* __restrict__ x,
    const float* __restrict__ bq,
    const float* __restrict__ bkv,
    const float* __restrict__ bp,
    const float* __restrict__ pos_bias,
    const f16* __restrict__ wqT,
    const f16* __restrict__ wkvT,
    const f16* __restrict__ wpT,
    f16* __restrict__ xf,
    float* __restrict__ out) {
  __shared__ char lds[90112];  // [0,81920): 2x40KB tile bufs; [81920,90112): as_

  const int tid = threadIdx.x;
  const int lane = tid & 63;
  const int w = tid >> 6;     // wave 0..15 = head (phase 2)
  const int c = lane & 15;
  const int g4 = lane >> 4;

  const int p = blockIdx.x;
  const int b = p >> 6;        // batch
  const int sg = p & 63;       // 256-s chunk
  const int tile_base = p * 16;

  // ================= phase 1: transpose own slice =================
  {
    float* ls = (float*)lds;   // 32 x 258 f32 = 33 KB
    for (int t = 0; t < 5; ++t) {
      for (int k0 = 0; k0 < 8; ++k0) {
        const float* xA = x + ((size_t)((b * 5 + t) * 256 + k0 * 32)) * SP
                            + sg * 256;
#pragma unroll
        for (int jj = 0; jj < 2; ++jj) {
          const int qq = jj * 1024 + tid;
          const int dl = qq >> 6, s4 = qq & 63;
          const f32x4 v = *(const f32x4*)(xA + (size_t)dl * SP + s4 * 4);
          *(f32x4*)&ls[dl * 258 + s4 * 4] = v;
        }
        __syncthreads();
        {
          const int tt = tid >> 6;          // 0..15 (= wave)
          const int cc = (tid >> 2) & 15;
          const int gg = tid & 3;
          f16x8 pk;
#pragma unroll
          for (int e = 0; e < 8; ++e)
            pk[e] = (f16)ls[(gg * 8 + e) * 258 + tt * 16 + cc];
          f16* dst = xf + (size_t)(tile_base + tt) * 20480 + t * 4096
                        + k0 * 512 + gg * 128 + cc * 8;
          *(f16x8*)dst = pk;
        }
        __syncthreads();
      }
    }
  }

  // ============ per-head constants (tile-invariant, head = w) ============
  float pb[5], bqr[4], bkr[4], bvr[4];
#pragma unroll
  for (int t = 0; t < 5; ++t) pb[t] = pos_bias[w * 5 + t];
#pragma unroll
  for (int rr = 0; rr < 4; ++rr) {
    bqr[rr] = bq[w * 16 + 4 * g4 + rr];
    bkr[rr] = bkv[w * 16 + 4 * g4 + rr];
    bvr[rr] = bkv[256 + w * 16 + 4 * g4 + rr];
  }
  const float bpv = bp[16 * w + c];
  const f16* wqp = wqT + (w * 16 + c) * 256;
  const f16* wkp = wkvT + (w * 16 + c) * 256;
  const f16* wvp = wkvT + (256 + w * 16 + c) * 256;
  const f16* wpp = wpT + (16 * w + c) * 256;

  const char* xfb = (const char*)xf + (size_t)tile_base * 40960;
  char* as_ = lds + 81920;

  // stage tile i into buffer buf: 40 x gll(16B) split over 16 waves
  auto stage = [&](int i, int buf) {
    const char* src = xfb + (size_t)i * 40960;
    char* dst = lds + buf * 40960;
    for (int j = w; j < 40; j += 16) {
      __builtin_amdgcn_global_load_lds(
          (const void __attribute__((address_space(1)))*)(src + j * 1024 + lane * 16),
          (void __attribute__((address_space(3)))*)(dst + j * 1024 + lane * 16),
          16, 0, 0);
    }
  };

  // ================= phase 2: 16 tiles, double-buffered =================
  stage(0, 0);
  __syncthreads();  // drains gll + phase-1 writes: buf0 ready

  for (int i = 0; i < 16; ++i) {
    if (i < 15) stage(i + 1, (i + 1) & 1);

    // ---- q/k/v k-loop on buf[i&1] (swapped MFMA: C[m=dk][n=s]) ----
    const char* fbp = lds + (i & 1) * 40960;
    f32x4 qa = {};
    f32x4 ka[5] = {};
    f32x4 va[5] = {};
#pragma unroll 1
    for (int k0 = 0; k0 < 8; ++k0) {
      const int kk = (k0 << 5) + (g4 << 3);
      const f16x8 fq = *(const f16x8*)(wqp + kk);
      const f16x8 fk = *(const f16x8*)(wkp + kk);
      const f16x8 fv = *(const f16x8*)(wvp + kk);
      const int base = (k0 << 10) + (g4 << 8) + (c << 4);
      f16x8 xfr[5];
#pragma unroll
      for (int t = 0; t < 5; ++t) xfr[t] = *(const f16x8*)(fbp + (t << 13) + base);
      qa = __builtin_amdgcn_mfma_f32_16x16x32_f16(fq, xfr[0], qa, 0, 0, 0);
#pragma unroll
      for (int t = 0; t < 5; ++t) {
        ka[t] = __builtin_amdgcn_mfma_f32_16x16x32_f16(fk, xfr[t], ka[t], 0, 0, 0);
        va[t] = __builtin_amdgcn_mfma_f32_16x16x32_f16(fv, xfr[t], va[t], 0, 0, 0);
      }
    }

    // ---- attention (lane holds q/k/v[dk=4g4+rr][s=c], head w) ----
    {
      float qv[4];
#pragma unroll
      for (int rr = 0; rr < 4; ++rr) qv[rr] = qa[rr] + bqr[rr];
      float sc[5];
#pragma unroll
      for (int t = 0; t < 5; ++t) {
        float pp = 0.f;
#pragma unroll
        for (int rr = 0; rr < 4; ++rr) pp += qv[rr] * (ka[t][rr] + bkr[rr]);
        pp += __shfl_xor(pp, 16);
        pp += __shfl_xor(pp, 32);
        sc[t] = pp * 4.0f + pb[t];  // /temperature (=0.25) + pos_bias
      }
      float m = sc[0];
#pragma unroll
      for (int t = 1; t < 5; ++t) m = fmaxf(m, sc[t]);
      float l = 0.f;
#pragma unroll
      for (int t = 0; t < 5; ++t) { sc[t] = __expf(sc[t] - m); l += sc[t]; }
      const float inv = 1.0f / l;
      union { f16 hh[4]; unsigned long long uu; } pk;
#pragma unroll
      for (int rr = 0; rr < 4; ++rr) {
        float o = 0.f;
#pragma unroll
        for (int t = 0; t < 5; ++t) o += sc[t] * (va[t][rr] + bvr[rr]);
        pk.hh[rr] = (f16)(o * inv);
      }
      const int byte = ((w >> 1) << 10) + (((2 * w + (g4 >> 1)) & 3) << 8)
                       + (c << 4) + ((g4 & 1) << 3);
      *(unsigned long long*)(as_ + byte) = pk.uu;
    }
    __syncthreads();  // as_ visible; stage(i+1) drained

    // ---- projection: wave w -> douts 16w..16w+15 ----
    f32x4 fa = {};
#pragma unroll 1
    for (int k0 = 0; k0 < 8; ++k0) {
      const int kk = (k0 << 5) + (g4 << 3);
      const f16x8 f0 = *(const f16x8*)(wpp + kk);
      const f16x8 af = *(const f16x8*)(as_ + (k0 << 10) + (g4 << 8) + (c << 4));
      fa = __builtin_amdgcn_mfma_f32_16x16x32_f16(af, f0, fa, 0, 0, 0);
    }
    {
      const int g = tile_base + i;
      const int s0 = (g & 1023) << 4;
      const int dg = 16 * w + c;
      f32x4 vs = fa;
#pragma unroll
      for (int rr = 0; rr < 4; ++rr) vs[rr] += bpv;
      *(f32x4*)(out + ((size_t)b * 256 + dg) * SP + s0 + (g4 << 2)) = vs;
    }
    __syncthreads();  // as_ reads done (next iter overwrites)
  }
}

extern "C" void kernel_launch(void* const* d_in, const int* in_sizes, int n_in,
                              void* d_out, int out_size, void* d_ws, size_t ws_size,
                              hipStream_t stream) {
  const float* x   = (const float*)d_in[0];
  const float* Wq  = (const float*)d_in[1];
  const float* bq  = (const float*)d_in[2];
  const float* Wkv = (const float*)d_in[3];
  const float* bkv = (const float*)d_in[4];
  const float* Wp  = (const float*)d_in[5];
  const float* bp  = (const float*)d_in[6];
  const float* pos = (const float*)d_in[7];

  f16* xf   = (f16*)d_ws;                      // 168 MB
  f16* wqT  = (f16*)((char*)d_ws + XF_BYTES);
  f16* wkvT = wqT + 256 * 256;
  f16* wpT  = wkvT + 512 * 256;

  prep_weights<<<256, 512, 0, stream>>>(Wq, Wkv, Wp, wqT, wkvT, wpT);
  mega<<<256, 1024, 0, stream>>>(x, bq, bkv, bp, pos, wqT, wkvT, wpT,
                                 xf, (float*)d_out);
}